// Round 7
// baseline (5272.684 us; speedup 1.0000x reference)
//
#include <hip/hip_runtime.h>
#include <math.h>

#define DIMX 512
#define NHEADS 8
#define DHE 64
#define NB 266
#define MP 288          // NB padded to 18 MFMA col-tiles
#define MT 18           // MP/16
#define KPT_LD 136      // kpT row stride (128+8) to break banks
#define CTXT_LD 296     // ctxt row stride (288+8)
#define NSTRIP 32       // strips per (b,h) in kctx
#define FFD 2048
#define OUTD 32
#define SEQ 8192
#define NTOK 32768
#define NLAYER 6
#define PSEQ 16384      // tokens per batch-pair
#define FC_PAD 516      // fc W LDS pad (mult of 4, stride mod 32 = 4)

#define DN_F 0.35355339059327373f
#define RATIO_F 0.06131393f
#define EPS_F 1e-4f

typedef unsigned short ushort_t;
typedef __attribute__((ext_vector_type(8))) short short8;
typedef __attribute__((ext_vector_type(4))) float floatx4;

// gelu(x) = 0.5x(1+tanh(z)) = x * sigmoid(2z), z = 0.79788456(x + 0.044715 x^3)
__device__ __forceinline__ float gelu_f(float x) {
    float s = x * x;
    float t = fmaf(0.044715f, s, 1.0f);
    float u = -1.5957691216057308f * x * t;     // -2z
    float e = __expf(u);
    return x * __builtin_amdgcn_rcpf(1.0f + e);
}

__device__ __forceinline__ ushort_t f2bf(float f) {
    unsigned int u = __float_as_uint(f);
    unsigned int r = (u + 0x7fffu + ((u >> 16) & 1u)) >> 16;
    return (ushort_t)r;
}

__device__ __forceinline__ float bf2f(ushort_t u) {
    return __uint_as_float(((unsigned int)u) << 16);
}

__device__ __forceinline__ unsigned int fkey(float f) {
    unsigned int u = __float_as_uint(f);
    return (u & 0x80000000u) ? ~u : (u | 0x80000000u);
}
__device__ __forceinline__ float funkey(unsigned int k) {
    unsigned int u = (k & 0x80000000u) ? (k & 0x7fffffffu) : ~k;
    return __uint_as_float(u);
}

// async global->LDS 16B per lane; LDS dest = wave-uniform base + lane*16
__device__ __forceinline__ void gl_lds16(const void* g, void* l) {
    __builtin_amdgcn_global_load_lds(
        (const __attribute__((address_space(1))) unsigned int*)g,
        (__attribute__((address_space(3))) unsigned int*)l, 16, 0, 0);
}

__global__ __launch_bounds__(256) void zero_kernel(float* __restrict__ p, int n) {
    int i = blockIdx.x * 256 + threadIdx.x;
    if (i < n) p[i] = 0.f;
}

// ---------------- LayerNorm -> bf16 out: one wave per 512-float row ----------------
__global__ __launch_bounds__(256) void ln_bf16_kernel(const float* __restrict__ x,
                                                      const float* __restrict__ g,
                                                      const float* __restrict__ b,
                                                      ushort_t* __restrict__ out) {
    int row = blockIdx.x * 4 + (threadIdx.x >> 6);
    int lane = threadIdx.x & 63;
    const float4* xr = (const float4*)(x + (size_t)row * DIMX);
    float4 v0 = xr[lane];
    float4 v1 = xr[lane + 64];
    float sum = v0.x + v0.y + v0.z + v0.w + v1.x + v1.y + v1.z + v1.w;
#pragma unroll
    for (int off = 32; off; off >>= 1) sum += __shfl_xor(sum, off);
    float mu = sum * (1.0f / 512.0f);
    float var = (v0.x - mu) * (v0.x - mu) + (v0.y - mu) * (v0.y - mu) +
                (v0.z - mu) * (v0.z - mu) + (v0.w - mu) * (v0.w - mu) +
                (v1.x - mu) * (v1.x - mu) + (v1.y - mu) * (v1.y - mu) +
                (v1.z - mu) * (v1.z - mu) + (v1.w - mu) * (v1.w - mu);
#pragma unroll
    for (int off = 32; off; off >>= 1) var += __shfl_xor(var, off);
    float rstd = rsqrtf(var * (1.0f / 512.0f) + 1e-5f);
    const float4* g4 = (const float4*)g;
    const float4* b4 = (const float4*)b;
    ushort_t* orow = out + (size_t)row * DIMX;
    float4 gg = g4[lane], bb = b4[lane];
    ushort4 o;
    o.x = f2bf((v0.x - mu) * rstd * gg.x + bb.x);
    o.y = f2bf((v0.y - mu) * rstd * gg.y + bb.y);
    o.z = f2bf((v0.z - mu) * rstd * gg.z + bb.z);
    o.w = f2bf((v0.w - mu) * rstd * gg.w + bb.w);
    *(ushort4*)(orow + lane * 4) = o;
    gg = g4[lane + 64]; bb = b4[lane + 64];
    o.x = f2bf((v1.x - mu) * rstd * gg.x + bb.x);
    o.y = f2bf((v1.y - mu) * rstd * gg.y + bb.y);
    o.z = f2bf((v1.z - mu) * rstd * gg.z + bb.z);
    o.w = f2bf((v1.w - mu) * rstd * gg.w + bb.w);
    *(ushort4*)(orow + 256 + lane * 4) = o;
}

// 4 square 512x512 weights in one launch (grid.z selects)
__global__ __launch_bounds__(256) void wconv4_kernel(const float* __restrict__ W0,
                                                     const float* __restrict__ W1,
                                                     const float* __restrict__ W2,
                                                     const float* __restrict__ W3,
                                                     ushort_t* __restrict__ Wt) {
    __shared__ float tile[32][33];
    const float* Ws[4] = {W0, W1, W2, W3};
    const float* W = Ws[blockIdx.z];
    ushort_t* Wd = Wt + (size_t)blockIdx.z * DIMX * DIMX;
    int bx = blockIdx.x * 32;
    int by = blockIdx.y * 32;
    int tx = threadIdx.x & 31, ty = threadIdx.x >> 5;
#pragma unroll
    for (int r = 0; r < 4; r++)
        tile[ty + r * 8][tx] = W[(size_t)(by + ty + r * 8) * DIMX + bx + tx];
    __syncthreads();
#pragma unroll
    for (int r = 0; r < 4; r++)
        Wd[(size_t)(bx + ty + r * 8) * DIMX + by + tx] = f2bf(tile[tx][ty + r * 8]);
}

// W1 [512,2048]->W1t and W2 [2048,512]->W2t in one launch (2048 blocks)
__global__ __launch_bounds__(256) void wconvFF_kernel(const float* __restrict__ W1,
                                                      const float* __restrict__ W2,
                                                      ushort_t* __restrict__ W1t,
                                                      ushort_t* __restrict__ W2t) {
    __shared__ float tile[32][33];
    int bid = blockIdx.x;
    const float* W;
    ushort_t* Wt;
    int K, N, bx, by;
    if (bid < 1024) {
        W = W1; Wt = W1t; K = 512; N = 2048;
        bx = (bid & 63) * 32; by = (bid >> 6) * 32;
    } else {
        bid -= 1024;
        W = W2; Wt = W2t; K = 2048; N = 512;
        bx = (bid & 15) * 32; by = (bid >> 4) * 32;
    }
    int tx = threadIdx.x & 31, ty = threadIdx.x >> 5;
#pragma unroll
    for (int r = 0; r < 4; r++)
        tile[ty + r * 8][tx] = W[(size_t)(by + ty + r * 8) * N + bx + tx];
    __syncthreads();
#pragma unroll
    for (int r = 0; r < 4; r++)
        Wt[(size_t)(bx + ty + r * 8) * K + by + tx] = f2bf(tile[tx][ty + r * 8]);
}

// ---------------- proj fp32 [266][64] -> bf16 [288][64] (pad rows zero); zero KMAX ----------
__global__ __launch_bounds__(256) void projconv_kernel(const float* __restrict__ proj,
                                                       ushort_t* __restrict__ Pbf,
                                                       unsigned int* __restrict__ KMAX) {
    int i = blockIdx.x * 256 + threadIdx.x;
    if (blockIdx.x == 0 && threadIdx.x < 4) KMAX[threadIdx.x] = 0u;
    if (i < MP * DHE) {
        int m = i >> 6;
        Pbf[i] = (m < NB) ? f2bf(proj[i]) : (ushort_t)0;
    }
}

// ---------------- bf16 MFMA GEMM: 128x128 tile, 16x16x32, 2-phase double-buffered ----------
// A[M,K] bf16 row-major; Bt[N,K] bf16 row-major. XCD-swizzled (nwg % 8 == 0).
// EPI 1: C = Cin + A@B + bias (fp32). EPI 2: Cb = bf16(gelu(A@B+bias)).
// EPI 4: transposed per-head bf16: Vt[(b*8+h)*64+d][8192].
// EPI 5: Cb = bf16(A@B) and SS[head][row] = sum over head cols of v^2.
template <int EPI>
__global__ __launch_bounds__(256) void gemm_mfma(const ushort_t* __restrict__ A,
                                                 const ushort_t* __restrict__ Bt,
                                                 const float* __restrict__ bias,
                                                 const float* Cin,
                                                 float* C,
                                                 ushort_t* __restrict__ Cb,
                                                 float* __restrict__ SS,
                                                 int M, int N, int K) {
    __shared__ ushort_t As[2][128 * 32];
    __shared__ ushort_t Bs[2][128 * 32];
    int t = threadIdx.x;
    int wave = t >> 6, lane = t & 63;
    int wm = wave >> 1, wn = wave & 1;
    // bijective XCD swizzle; decode n-fastest so each XCD owns a contiguous m-panel
    int gy = gridDim.y;
    int orig = blockIdx.x + blockIdx.y * gridDim.x;
    int cpx = (gridDim.x * gy) >> 3;
    int swz = (orig & 7) * cpx + (orig >> 3);
    int m0 = (swz / gy) * 128, n0 = (swz - (swz / gy) * gy) * 128;
    int q = lane >> 4, ml = lane & 15;

    floatx4 acc[4][4];
#pragma unroll
    for (int i = 0; i < 4; i++)
#pragma unroll
        for (int j = 0; j < 4; j++) acc[i][j] = (floatx4)(0.f);

    int srow = (lane >> 2);
    int scol = (lane & 3) * 8;
    const ushort_t* Ag = A + (size_t)(m0 + wave * 32 + srow) * K + scol;
    const ushort_t* Bg = Bt + (size_t)(n0 + wave * 32 + srow) * K + scol;
    ushort_t* AsW[2] = {&As[0][(wave * 32) * 32], &As[1][(wave * 32) * 32]};
    ushort_t* BsW[2] = {&Bs[0][(wave * 32) * 32], &Bs[1][(wave * 32) * 32]};

    gl_lds16(Ag, AsW[0]);
    gl_lds16(Ag + (size_t)16 * K, AsW[0] + 16 * 32);
    gl_lds16(Bg, BsW[0]);
    gl_lds16(Bg + (size_t)16 * K, BsW[0] + 16 * 32);
    __syncthreads();

    int cur = 0;
    for (int k0 = 32; k0 < K; k0 += 32) {
        int nxt = cur ^ 1;
        gl_lds16(Ag + k0, AsW[nxt]);
        gl_lds16(Ag + k0 + (size_t)16 * K, AsW[nxt] + 16 * 32);
        gl_lds16(Bg + k0, BsW[nxt]);
        gl_lds16(Bg + k0 + (size_t)16 * K, BsW[nxt] + 16 * 32);
        const ushort_t* Ac = &As[cur][0];
        const ushort_t* Bc = &Bs[cur][0];
        short8 a[4], b[4];
#pragma unroll
        for (int i = 0; i < 4; i++)
            a[i] = *(const short8*)&Ac[(wm * 64 + i * 16 + ml) * 32 + q * 8];
#pragma unroll
        for (int j = 0; j < 4; j++)
            b[j] = *(const short8*)&Bc[(wn * 64 + j * 16 + ml) * 32 + q * 8];
#pragma unroll
        for (int i = 0; i < 4; i++)
#pragma unroll
            for (int j = 0; j < 4; j++)
                acc[i][j] = __builtin_amdgcn_mfma_f32_16x16x32_bf16(a[i], b[j], acc[i][j], 0, 0, 0);
        __syncthreads();
        cur = nxt;
    }
    {
        const ushort_t* Ac = &As[cur][0];
        const ushort_t* Bc = &Bs[cur][0];
        short8 a[4], b[4];
#pragma unroll
        for (int i = 0; i < 4; i++)
            a[i] = *(const short8*)&Ac[(wm * 64 + i * 16 + ml) * 32 + q * 8];
#pragma unroll
        for (int j = 0; j < 4; j++)
            b[j] = *(const short8*)&Bc[(wn * 64 + j * 16 + ml) * 32 + q * 8];
#pragma unroll
        for (int i = 0; i < 4; i++)
#pragma unroll
            for (int j = 0; j < 4; j++)
                acc[i][j] = __builtin_amdgcn_mfma_f32_16x16x32_bf16(a[i], b[j], acc[i][j], 0, 0, 0);
    }

    if (EPI == 4) {
#pragma unroll
        for (int i = 0; i < 4; i++) {
            size_t r0 = (size_t)m0 + wm * 64 + i * 16 + q * 4;
            int bb = (int)(r0 >> 13);
            int nl = (int)(r0 & (SEQ - 1));
#pragma unroll
            for (int j = 0; j < 4; j++) {
                int col = n0 + wn * 64 + j * 16 + ml;
                int hh = col >> 6, dd = col & 63;
                ushort4 pk;
                pk.x = f2bf(acc[i][j][0]); pk.y = f2bf(acc[i][j][1]);
                pk.z = f2bf(acc[i][j][2]); pk.w = f2bf(acc[i][j][3]);
                *(ushort4*)&Cb[(((size_t)bb * 8 + hh) * DHE + dd) * SEQ + nl] = pk;
            }
        }
    } else if (EPI == 5) {
        int hh = (n0 >> 6) + wn;  // each wave's 64 cols = one head
#pragma unroll
        for (int i = 0; i < 4; i++) {
#pragma unroll
            for (int r = 0; r < 4; r++) {
                size_t row = (size_t)m0 + wm * 64 + i * 16 + q * 4 + r;
                float sq = 0.f;
#pragma unroll
                for (int j = 0; j < 4; j++) {
                    int col = n0 + wn * 64 + j * 16 + ml;
                    float v = acc[i][j][r];
                    sq += v * v;
                    Cb[row * N + col] = f2bf(v);
                }
                sq += __shfl_xor(sq, 1);
                sq += __shfl_xor(sq, 2);
                sq += __shfl_xor(sq, 4);
                sq += __shfl_xor(sq, 8);
                if (ml == 0) SS[(size_t)hh * PSEQ + row] = sq;
            }
        }
    } else {
#pragma unroll
        for (int i = 0; i < 4; i++) {
#pragma unroll
            for (int r = 0; r < 4; r++) {
                size_t row = (size_t)m0 + wm * 64 + i * 16 + q * 4 + r;
#pragma unroll
                for (int j = 0; j < 4; j++) {
                    int col = n0 + wn * 64 + j * 16 + ml;
                    float v = acc[i][j][r];
                    if (EPI == 1) {
                        C[row * N + col] = Cin[row * N + col] + v + bias[col];
                    } else if (EPI == 2) {
                        Cb[row * N + col] = f2bf(gelu_f(v + bias[col]));
                    }
                }
            }
        }
    }
}

// ---------------- dedicated fc: out[M,32] = X[M,512] @ W[512,32] + b ----------------
// 2048 blocks x 256 threads; W^T staged in LDS (pad 516); each wave does 4 rows;
// lane = (col 0..31, khalf 0..1); broadcast float4 X loads; shfl_xor(32) reduce.
__global__ __launch_bounds__(256) void fc_kernel(const float* __restrict__ A,
                                                 const float* __restrict__ W,
                                                 const float* __restrict__ bias,
                                                 float* __restrict__ C) {
    __shared__ float Wl[32 * FC_PAD];
    int tid = threadIdx.x;
    for (int e = tid; e < 512 * 32; e += 256) {
        int k = e >> 5, col = e & 31;
        Wl[col * FC_PAD + k] = W[e];
    }
    __syncthreads();
    int w = tid >> 6, lane = tid & 63;
    int col = lane & 31, kh = lane >> 5;
    size_t row0 = (size_t)blockIdx.x * 16 + w * 4;
    const float* Wp = &Wl[col * FC_PAD + kh * 256];
    const float4* x0 = (const float4*)(A + row0 * DIMX) + kh * 64;
    const float4* x1 = (const float4*)(A + (row0 + 1) * DIMX) + kh * 64;
    const float4* x2 = (const float4*)(A + (row0 + 2) * DIMX) + kh * 64;
    const float4* x3 = (const float4*)(A + (row0 + 3) * DIMX) + kh * 64;
    float acc0 = 0.f, acc1 = 0.f, acc2 = 0.f, acc3 = 0.f;
#pragma unroll 8
    for (int k4 = 0; k4 < 64; k4++) {
        float4 wv = *(const float4*)(Wp + k4 * 4);
        float4 a0 = x0[k4], a1 = x1[k4], a2 = x2[k4], a3 = x3[k4];
        acc0 += a0.x * wv.x + a0.y * wv.y + a0.z * wv.z + a0.w * wv.w;
        acc1 += a1.x * wv.x + a1.y * wv.y + a1.z * wv.z + a1.w * wv.w;
        acc2 += a2.x * wv.x + a2.y * wv.y + a2.z * wv.z + a2.w * wv.w;
        acc3 += a3.x * wv.x + a3.y * wv.y + a3.z * wv.z + a3.w * wv.w;
    }
    acc0 += __shfl_xor(acc0, 32);
    acc1 += __shfl_xor(acc1, 32);
    acc2 += __shfl_xor(acc2, 32);
    acc3 += __shfl_xor(acc3, 32);
    if (kh == 0) {
        float bb = bias[col];
        C[(row0 + 0) * OUTD + col] = acc0 + bb;
        C[(row0 + 1) * OUTD + col] = acc1 + bb;
        C[(row0 + 2) * OUTD + col] = acc2 + bb;
        C[(row0 + 3) * OUTD + col] = acc3 + bb;
    }
}

// ---------------- global key-feature max via MFMA: grid 512 = 8 heads x 64 tiles ------------
__global__ __launch_bounds__(512) void kmax_kernel(const ushort_t* __restrict__ Kbf,
                                                   const ushort_t* __restrict__ Pbf,
                                                   unsigned int* __restrict__ kmaxkey) {
    __shared__ float wred[8];
    int tid = threadIdx.x;
    int w = tid >> 6, lane = tid & 63;
    int q = lane >> 4, ml = lane & 15;
    int h = blockIdx.x >> 6, tile = blockIdx.x & 63;
    float lm = -3.0e38f;
#pragma unroll
    for (int sub = 0; sub < 2; sub++) {
        int arow = tile * 256 + sub * 128 + w * 16 + ml;
        short8 af0 = *(const short8*)&Kbf[(size_t)arow * DIMX + h * DHE + q * 8];
        short8 af1 = *(const short8*)&Kbf[(size_t)arow * DIMX + h * DHE + 32 + q * 8];
#pragma unroll
        for (int c = 0; c < 17; c++) {
            floatx4 xp = (floatx4)(0.f);
            short8 b0 = *(const short8*)&Pbf[(c * 16 + ml) * DHE + q * 8];
            short8 b1 = *(const short8*)&Pbf[(c * 16 + ml) * DHE + 32 + q * 8];
            xp = __builtin_amdgcn_mfma_f32_16x16x32_bf16(af0, b0, xp, 0, 0, 0);
            xp = __builtin_amdgcn_mfma_f32_16x16x32_bf16(af1, b1, xp, 0, 0, 0);
            if (c * 16 + ml < NB)
                lm = fmaxf(lm, fmaxf(fmaxf(xp[0], xp[1]), fmaxf(xp[2], xp[3])));
        }
    }
    lm *= DN_F;
#pragma unroll
    for (int off = 32; off; off >>= 1) lm = fmaxf(lm, __shfl_xor(lm, off));
    if (lane == 0) wred[w] = lm;
    __syncthreads();
    if (tid == 0) {
        float bm = wred[0];
#pragma unroll
        for (int ww = 1; ww < 8; ww++) bm = fmaxf(bm, wred[ww]);
        atomicMax(kmaxkey, fkey(bm));
    }
}

// ---------------- fused kp + CTX partial via MFMA (half-split kpT, 2 blocks/CU) ------------
// CTXP partials streamed with nontemporal stores (bypass L2 write-allocate/thrash).
__global__ __launch_bounds__(512, 4) void kctx_kernel(const ushort_t* __restrict__ Kbf,
                                                      const ushort_t* __restrict__ Pbf,
                                                      const float* __restrict__ SS,
                                                      const unsigned int* __restrict__ kmaxkey,
                                                      const ushort_t* __restrict__ Vt,
                                                      float* __restrict__ CTXP,
                                                      float* __restrict__ KSUM) {
    __shared__ ushort_t kpT[144 * KPT_LD];   // 39168 B; reused as float[144][68] for output
    __shared__ float ksum_l[MP];
    int tid = threadIdx.x;
    int w = tid >> 6, lane = tid & 63;
    int q = lane >> 4, ml = lane & 15;
    int bh = blockIdx.x >> 5, s = blockIdx.x & 31;
    int b = bh >> 3, h = bh & 7;
    float mx = funkey(*kmaxkey);
    if (tid < MP) ksum_l[tid] = 0.f;
    __syncthreads();
    floatx4 ctxa[2][5];
#pragma unroll
    for (int hf = 0; hf < 2; hf++)
#pragma unroll
        for (int i = 0; i < 5; i++) ctxa[hf][i] = (floatx4)(0.f);

#pragma unroll
    for (int sub = 0; sub < 2; sub++) {
        int tb = b * SEQ + s * 256 + sub * 128;
        int arow = tb + w * 16 + ml;
        short8 af0 = *(const short8*)&Kbf[(size_t)arow * DIMX + h * DHE + q * 8];
        short8 af1 = *(const short8*)&Kbf[(size_t)arow * DIMX + h * DHE + 32 + q * 8];
        float ssr[4];
#pragma unroll
        for (int r = 0; r < 4; r++) ssr[r] = SS[h * PSEQ + tb + w * 16 + q * 4 + r];
#pragma unroll
        for (int hf = 0; hf < 2; hf++) {
#pragma unroll
            for (int cl = 0; cl < 9; cl++) {
                int c = hf * 9 + cl;
                floatx4 xp = (floatx4)(0.f);
                short8 b0 = *(const short8*)&Pbf[(c * 16 + ml) * DHE + q * 8];
                short8 b1 = *(const short8*)&Pbf[(c * 16 + ml) * DHE + 32 + q * 8];
                xp = __builtin_amdgcn_mfma_f32_16x16x32_bf16(af0, b0, xp, 0, 0, 0);
                xp = __builtin_amdgcn_mfma_f32_16x16x32_bf16(af1, b1, xp, 0, 0, 0);
                int m = c * 16 + ml;
                bool val = m < NB;
                float kpv[4];
#pragma unroll
                for (int r = 0; r < 4; r++)
                    kpv[r] = val ? RATIO_F * (__expf(xp[r] * DN_F - ssr[r] * 0.0625f - mx) + EPS_F)
                                 : 0.f;
                ushort4 pk;
                pk.x = f2bf(kpv[0]); pk.y = f2bf(kpv[1]);
                pk.z = f2bf(kpv[2]); pk.w = f2bf(kpv[3]);
                *(ushort4*)&kpT[(cl * 16 + ml) * KPT_LD + w * 16 + q * 4] = pk;
                float s4 = kpv[0] + kpv[1] + kpv[2] + kpv[3];
                s4 += __shfl_xor(s4, 16);
                s4 += __shfl_xor(s4, 32);
                if (q == 0) atomicAdd(&ksum_l[m], s4);
            }
            __syncthreads();
#pragma unroll
            for (int sk = 0; sk < 4; sk++) {
#pragma unroll
                for (int i = 0; i < 5; i++) {
                    if (i < 4 || w < 4) {
                        int tt = w + i * 8;
                        int mtl = tt >> 2, dt = tt & 3;
                        short8 a = *(const short8*)&kpT[(mtl * 16 + ml) * KPT_LD + sk * 32 + q * 8];
                        short8 bv = *(const short8*)&Vt[((size_t)bh * DHE + dt * 16 + ml) * SEQ +
                                                        s * 256 + sub * 128 + sk * 32 + q * 8];
                        ctxa[hf][i] = __builtin_amdgcn_mfma_f32_16x16x32_bf16(a, bv, ctxa[hf][i], 0, 0, 0);
                    }
                }
            }
            __syncthreads();
        }
    }
    // --- coalesced output: stage each half through LDS, stream nontemporal float4 ---
    float* stg = (float*)kpT;   // [144][68] floats
    float* cp = CTXP + ((size_t)bh * NSTRIP + s) * (MP * DHE);
#pragma unroll
    for (int hf = 0; hf < 2; hf++) {
        __syncthreads();
#pragma unroll
        for (int i = 0; i < 5; i++) {
            if (i < 4 || w < 4) {
                int tt = w + i * 8;
                int mtl = tt >> 2, dt = tt & 3;
#pragma unroll
                for (int r = 0; r < 4; r++)
                    stg[(mtl * 16 + q * 4 + r) * 68 + dt * 16 + ml] = ctxa[hf][i][r];
            }
        }
        __syncthreads();
        floatx4* cp4 = (floatx4*)(cp + (size_t)hf * 144 * DHE);
        for (int e4 = tid; e4 < 2304; e4 += 512) {
            int row = e4 >> 4, col4 = e4 & 15;
            floatx4 v = ((const floatx4*)stg)[row * 17 + col4];
            __builtin_nontemporal_store(v, &cp4[e4]);
        }
    }
    if (tid < MP) atomicAdd(&KSUM[bh * MP + tid], ksum_l[tid]);
}

// -------- reduce CTX partials over 32 strips (nontemporal); emit bf16 CTX^T --------
__global__ __launch_bounds__(256) void ctx_reduce_kernel(const float* __restrict__ CTXP,
                                                         ushort_t* __restrict__ CTXbf) {
    int i = blockIdx.x * 256 + threadIdx.x;  // 16*288*64
    if (i < 16 * MP * DHE) {
        int bh = i / (MP * DHE);
        int e = i - bh * (MP * DHE);
        float s = 0.f;
#pragma unroll
        for (int st = 0; st < NSTRIP; st++)
            s += __builtin_nontemporal_load(&CTXP[((size_t)bh * NSTRIP + st) * (MP * DHE) + e]);
        int m = e >> 6, d = e & 63;
        CTXbf[((size_t)bh * DHE + d) * CTXT_LD + m] = f2bf(s);
    }
}

// ---------------- fused qp + rowmax + denom + O = dinv*(qp@CTX) via MFMA ----------------
__global__ __launch_bounds__(256, 3) void qo_kernel(const ushort_t* __restrict__ Qbf,
                                                    const ushort_t* __restrict__ Pbf,
                                                    const float* __restrict__ SS,
                                                    const ushort_t* __restrict__ CTXbf,
                                                    const float* __restrict__ KSUM,
                                                    ushort_t* __restrict__ Ob) {
    __shared__ ushort_t ctxt[DHE * CTXT_LD];
    __shared__ ushort_t qpA[4][16][40];
    __shared__ float ksl[MP];
    int tid = threadIdx.x;
    int w = tid >> 6, lane = tid & 63;
    int q = lane >> 4, ml = lane & 15;
    int bh = blockIdx.x >> 7, tile = blockIdx.x & 127;
    int b = bh >> 3, h = bh & 7;
    const short8* Cg8 = (const short8*)(CTXbf + (size_t)bh * (DHE * CTXT_LD));
    short8* ct8 = (short8*)ctxt;
    for (int e = tid; e < (DHE * CTXT_LD) / 8; e += 256)
        ct8[e] = Cg8[e];
    ksl[tid] = KSUM[bh * MP + tid];
    if (tid < MP - 256) ksl[256 + tid] = KSUM[bh * MP + 256 + tid];
    __syncthreads();
    int nl = tile * 64 + w * 16;
    int arow = b * SEQ + nl + ml;
    short8 af0 = *(const short8*)&Qbf[(size_t)arow * DIMX + h * DHE + q * 8];
    short8 af1 = *(const short8*)&Qbf[(size_t)arow * DIMX + h * DHE + 32 + q * 8];
    floatx4 xp[MT];
#pragma unroll
    for (int c = 0; c < MT; c++) {
        xp[c] = (floatx4)(0.f);
        short8 b0 = *(const short8*)&Pbf[(c * 16 + ml) * DHE + q * 8];
        short8 b1 = *(const short8*)&Pbf[(c * 16 + ml) * DHE + 32 + q * 8];
        xp[c] = __builtin_amdgcn_mfma_f32_16x16x32_bf16(af0, b0, xp[c], 0, 0, 0);
        xp[c] = __builtin_amdgcn_mfma_f32_16x16x32_bf16(af1, b1, xp[c], 0, 0, 0);
    }
    float ssr[4], rm[4], dp[4], dinv[4];
#pragma unroll
    for (int r = 0; r < 4; r++) {
        ssr[r] = SS[h * PSEQ + b * SEQ + nl + q * 4 + r];
        rm[r] = -3.0e38f;
        dp[r] = 0.f;
    }
#pragma unroll
    for (int c = 0; c < MT; c++) {
        int m = c * 16 + ml;
        bool val = m < NB;
#pragma unroll
        for (int r = 0; r < 4; r++) {
            float tv = xp[c][r] * DN_F;
            xp[c][r] = tv;
            if (val) rm[r] = fmaxf(rm[r], tv);
        }
    }
#pragma unroll
    for (int r = 0; r < 4; r++) {
        rm[r] = fmaxf(rm[r], __shfl_xor(rm[r], 1));
        rm[r] = fmaxf(rm[r], __shfl_xor(rm[r], 2));
        rm[r] = fmaxf(rm[r], __shfl_xor(rm[r], 4));
        rm[r] = fmaxf(rm[r], __shfl_xor(rm[r], 8));
    }
#pragma unroll
    for (int c = 0; c < MT; c++) {
        int m = c * 16 + ml;
        bool val = m < NB;
        float km = ksl[m];
#pragma unroll
        for (int r = 0; r < 4; r++) {
            float v = val ? RATIO_F * (__expf(xp[c][r] - ssr[r] * 0.0625f - rm[r]) + EPS_F) : 0.f;
            xp[c][r] = v;
            dp[r] += v * km;
        }
    }
#pragma unroll
    for (int r = 0; r < 4; r++) {
        dp[r] += __shfl_xor(dp[r], 1);
        dp[r] += __shfl_xor(dp[r], 2);
        dp[r] += __shfl_xor(dp[r], 4);
        dp[r] += __shfl_xor(dp[r], 8);
        dinv[r] = 1.0f / dp[r];
    }
    floatx4 oacc[4];
#pragma unroll
    for (int dt = 0; dt < 4; dt++) oacc[dt] = (floatx4)(0.f);
#pragma unroll
    for (int ks = 0; ks < 9; ks++) {
#pragma unroll
        for (int cc = 0; cc < 2; cc++) {
            int c = 2 * ks + cc;
#pragma unroll
            for (int r = 0; r < 4; r++)
                qpA[w][q * 4 + r][cc * 16 + ml] = f2bf(xp[c][r]);
        }
        short8 a = *(const short8*)&qpA[w][ml][q * 8];
#pragma unroll
        for (int dt = 0; dt < 4; dt++) {
            short8 bv = *(const short8*)&ctxt[(dt * 16 + ml) * CTXT_LD + ks * 32 + q * 8];
            oacc[dt] = __builtin_amdgcn_mfma_f32_16x16x32_bf16(a, bv, oacc[dt], 0, 0, 0);
        }
    }
#pragma unroll
    for (int dt = 0; dt < 4; dt++)
#pragma unroll
        for (int r = 0; r < 4; r++)
            Ob[(size_t)(b * SEQ + nl + q * 4 + r) * DIMX + h * DHE + dt * 16 + ml] =
                f2bf(oacc[dt][r] * dinv[r]);
}

extern "C" void kernel_launch(void* const* d_in, const int* in_sizes, int n_in,
                              void* d_out, int out_size, void* d_ws, size_t ws_size,
                              hipStream_t stream) {
    (void)in_sizes; (void)n_in; (void)out_size; (void)ws_size;
    const float* src  = (const float*)d_in[0];
    const float* proj = (const float*)d_in[1];
    const float* ln1g = (const float*)d_in[2];
    const float* ln1b = (const float*)d_in[3];
    const float* Wq   = (const float*)d_in[4];
    const float* Wk   = (const float*)d_in[5];
    const float* Wv   = (const float*)d_in[6];
    const float* Wo   = (const float*)d_in[7];
    const float* bo   = (const float*)d_in[8];
    const float* ln2g = (const float*)d_in[9];
    const float* ln2b = (const float*)d_in[10];
    const float* W1   = (const float*)d_in[11];
    const float* b1   = (const float*)d_in[12];
    const float* W2   = (const float*)d_in[13];
    const float* b2   = (const float*)d_in[14];
    const float* fcw  = (const float*)d_in[15];
    const float* fcb  = (const float*)d_in[16];
    float* out = (float*)d_out;

    // ---- workspace layout (~155 MiB of 162 safe) ----
    const size_t TD   = (size_t)NTOK * DIMX;
    const size_t PD   = (size_t)PSEQ * DIMX;
    float*    X    = (float*)d_ws;                      // 64 MiB residual fp32
    ushort_t* Hs   = (ushort_t*)(X + TD);               // 16 MiB LN out bf16 (pair)
    ushort_t* KQbf = Hs + PD;                           // 16 MiB K bf16, then Q bf16
    ushort_t* Vt   = KQbf + PD;                         // 16 MiB V^T per-head bf16
    float*    CTXP = (float*)(Vt + PD);                 // 36 MiB ctx partials (32 strips)
    ushort_t* Obuf = (ushort_t*)CTXP;                   // 16 MiB attn-out bf16, aliases CTXP
    ushort_t* CTXbf = (ushort_t*)(CTXP + (size_t)16 * NSTRIP * MP * DHE);  // bf16 CTX^T
    float*    KSUM = (float*)(CTXbf + (size_t)16 * DHE * CTXT_LD);  // 16x288
    unsigned int* KMAX = (unsigned int*)(KSUM + 16 * MP);
    float*    SS   = (float*)(KMAX + 4);                // [8][PSEQ]
    ushort_t* Pbf  = (ushort_t*)(SS + (size_t)NHEADS * PSEQ);  // [288][64] bf16
    ushort_t* Wtb  = Pbf + MP * DHE;                    // 6 MiB weights bf16
    ushort_t* Wqt = Wtb;
    ushort_t* Wkt = Wqt + DIMX * DIMX;
    ushort_t* Wvt = Wkt + DIMX * DIMX;
    ushort_t* Wot = Wvt + DIMX * DIMX;
    ushort_t* W1t = Wot + DIMX * DIMX;         // [FFD, DIMX]
    ushort_t* W2t = W1t + (size_t)DIMX * FFD;  // [DIMX, FFD]
    ushort_t* Hid = KQbf;  // FF hidden 64 MiB alias (all dead in FF)

    dim3 gP(PSEQ / 128, DIMX / 128);   // (128,4)  nwg=512
    dim3 gF1(PSEQ / 128, FFD / 128);   // (128,16) nwg=2048
    const int lnGrid = PSEQ / 4;
    for (int L = 0; L < NLAYER; L++) {
        const float* pj = proj + (size_t)L * NB * DHE;
        wconv4_kernel<<<dim3(16, 16, 4), 256, 0, stream>>>(
            Wq + (size_t)L * DIMX * DIMX, Wk + (size_t)L * DIMX * DIMX,
            Wv + (size_t)L * DIMX * DIMX, Wo + (size_t)L * DIMX * DIMX, Wqt);
        wconvFF_kernel<<<2048, 256, 0, stream>>>(W1 + (size_t)L * DIMX * FFD,
                                                 W2 + (size_t)L * FFD * DIMX, W1t, W2t);
        projconv_kernel<<<(MP * DHE + 255) / 256, 256, 0, stream>>>(pj, Pbf, KMAX);
        // --- phase A: global key-feature max over both pairs ---
        for (int p = 0; p < 2; p++) {
            const float* XpIn = (L == 0) ? (src + (size_t)p * PD) : (X + (size_t)p * PD);
            ln_bf16_kernel<<<lnGrid, 256, 0, stream>>>(XpIn, ln1g + L * DIMX, ln1b + L * DIMX, Hs);
            gemm_mfma<5><<<gP, 256, 0, stream>>>(Hs, Wkt, nullptr, nullptr, nullptr, KQbf, SS, PSEQ, DIMX, DIMX);
            kmax_kernel<<<512, 512, 0, stream>>>(KQbf, Pbf, KMAX);
        }
        // --- phase B: attention + FF per pair (p=1 first: Hs/KQbf/SS still hold pair-1) ---
        for (int pp = 0; pp < 2; pp++) {
            int p = 1 - pp;
            float* Xp = X + (size_t)p * PD;
            const float* XpIn = (L == 0) ? (src + (size_t)p * PD) : Xp;
            if (p == 0) {
                ln_bf16_kernel<<<lnGrid, 256, 0, stream>>>(XpIn, ln1g + L * DIMX, ln1b + L * DIMX, Hs);
                gemm_mfma<5><<<gP, 256, 0, stream>>>(Hs, Wkt, nullptr, nullptr, nullptr, KQbf, SS, PSEQ, DIMX, DIMX);
            }
            gemm_mfma<4><<<gP, 256, 0, stream>>>(Hs, Wvt, nullptr, nullptr, nullptr, Vt, nullptr, PSEQ, DIMX, DIMX);
            zero_kernel<<<(16 * MP + 255) / 256, 256, 0, stream>>>(KSUM, 16 * MP);
            kctx_kernel<<<16 * NSTRIP, 512, 0, stream>>>(KQbf, Pbf, SS, KMAX, Vt, CTXP, KSUM);
            ctx_reduce_kernel<<<(16 * MP * DHE + 255) / 256, 256, 0, stream>>>(CTXP, CTXbf);
            gemm_mfma<5><<<gP, 256, 0, stream>>>(Hs, Wqt, nullptr, nullptr, nullptr, KQbf, SS, PSEQ, DIMX, DIMX);
            qo_kernel<<<2048, 256, 0, stream>>>(KQbf, Pbf, SS, CTXbf, KSUM, Obuf);
            // Wo: X = XpIn + Obuf@Wo + bo (layer 0 reads src, writes X)
            gemm_mfma<1><<<gP, 256, 0, stream>>>(Obuf, Wot, bo + L * DIMX, XpIn, Xp, nullptr, nullptr, PSEQ, DIMX, DIMX);
            // --- FF ---
            ln_bf16_kernel<<<lnGrid, 256, 0, stream>>>(Xp, ln2g + L * DIMX, ln2b + L * DIMX, Hs);
            gemm_mfma<2><<<gF1, 256, 0, stream>>>(Hs, W1t, b1 + L * FFD, nullptr, nullptr, Hid, nullptr, PSEQ, FFD, DIMX);
            gemm_mfma<1><<<gP, 256, 0, stream>>>(Hid, W2t, b2 + L * DIMX, Xp, Xp, nullptr, nullptr, PSEQ, DIMX, FFD);
        }
    }
    fc_kernel<<<NTOK / 16, 256, 0, stream>>>(X, fcw, fcb, out);
}

// Round 8
// 5029.607 us; speedup vs baseline: 1.0483x; 1.0483x over previous
//
#include <hip/hip_runtime.h>
#include <math.h>

#define DIMX 512
#define NHEADS 8
#define DHE 64
#define NB 266
#define MP 288          // NB padded to 18 MFMA col-tiles
#define MT 18           // MP/16
#define KPT_LD 136      // kpT row stride (128+8) to break banks
#define CTXT_LD 296     // ctxt row stride (288+8)
#define NSTRIP 32       // strips per (b,h) in kctx
#define FFD 2048
#define OUTD 32
#define SEQ 8192
#define NTOK 32768
#define NLAYER 6
#define PSEQ 16384      // tokens per batch-pair

#define DN_F 0.35355339059327373f
#define RATIO_F 0.06131393f
#define EPS_F 1e-4f

typedef unsigned short ushort_t;
typedef __attribute__((ext_vector_type(8))) short short8;
typedef __attribute__((ext_vector_type(4))) float floatx4;

// gelu(x) = 0.5x(1+tanh(z)) = x * sigmoid(2z), z = 0.79788456(x + 0.044715 x^3)
__device__ __forceinline__ float gelu_f(float x) {
    float s = x * x;
    float t = fmaf(0.044715f, s, 1.0f);
    float u = -1.5957691216057308f * x * t;     // -2z
    float e = __expf(u);
    return x * __builtin_amdgcn_rcpf(1.0f + e);
}

__device__ __forceinline__ ushort_t f2bf(float f) {
    unsigned int u = __float_as_uint(f);
    unsigned int r = (u + 0x7fffu + ((u >> 16) & 1u)) >> 16;
    return (ushort_t)r;
}

__device__ __forceinline__ float bf2f(ushort_t u) {
    return __uint_as_float(((unsigned int)u) << 16);
}

__device__ __forceinline__ unsigned int fkey(float f) {
    unsigned int u = __float_as_uint(f);
    return (u & 0x80000000u) ? ~u : (u | 0x80000000u);
}
__device__ __forceinline__ float funkey(unsigned int k) {
    unsigned int u = (k & 0x80000000u) ? (k & 0x7fffffffu) : ~k;
    return __uint_as_float(u);
}

// async global->LDS 16B per lane; LDS dest = wave-uniform base + lane*16
__device__ __forceinline__ void gl_lds16(const void* g, void* l) {
    __builtin_amdgcn_global_load_lds(
        (const __attribute__((address_space(1))) unsigned int*)g,
        (__attribute__((address_space(3))) unsigned int*)l, 16, 0, 0);
}

__global__ __launch_bounds__(256) void zero_kernel(float* __restrict__ p, int n) {
    int i = blockIdx.x * 256 + threadIdx.x;
    if (i < n) p[i] = 0.f;
}

// ---------------- LayerNorm -> bf16 out: one wave per 512-float row ----------------
__global__ __launch_bounds__(256) void ln_bf16_kernel(const float* __restrict__ x,
                                                      const float* __restrict__ g,
                                                      const float* __restrict__ b,
                                                      ushort_t* __restrict__ out) {
    int row = blockIdx.x * 4 + (threadIdx.x >> 6);
    int lane = threadIdx.x & 63;
    const float4* xr = (const float4*)(x + (size_t)row * DIMX);
    float4 v0 = xr[lane];
    float4 v1 = xr[lane + 64];
    float sum = v0.x + v0.y + v0.z + v0.w + v1.x + v1.y + v1.z + v1.w;
#pragma unroll
    for (int off = 32; off; off >>= 1) sum += __shfl_xor(sum, off);
    float mu = sum * (1.0f / 512.0f);
    float var = (v0.x - mu) * (v0.x - mu) + (v0.y - mu) * (v0.y - mu) +
                (v0.z - mu) * (v0.z - mu) + (v0.w - mu) * (v0.w - mu) +
                (v1.x - mu) * (v1.x - mu) + (v1.y - mu) * (v1.y - mu) +
                (v1.z - mu) * (v1.z - mu) + (v1.w - mu) * (v1.w - mu);
#pragma unroll
    for (int off = 32; off; off >>= 1) var += __shfl_xor(var, off);
    float rstd = rsqrtf(var * (1.0f / 512.0f) + 1e-5f);
    const float4* g4 = (const float4*)g;
    const float4* b4 = (const float4*)b;
    ushort_t* orow = out + (size_t)row * DIMX;
    float4 gg = g4[lane], bb = b4[lane];
    ushort4 o;
    o.x = f2bf((v0.x - mu) * rstd * gg.x + bb.x);
    o.y = f2bf((v0.y - mu) * rstd * gg.y + bb.y);
    o.z = f2bf((v0.z - mu) * rstd * gg.z + bb.z);
    o.w = f2bf((v0.w - mu) * rstd * gg.w + bb.w);
    *(ushort4*)(orow + lane * 4) = o;
    gg = g4[lane + 64]; bb = b4[lane + 64];
    o.x = f2bf((v1.x - mu) * rstd * gg.x + bb.x);
    o.y = f2bf((v1.y - mu) * rstd * gg.y + bb.y);
    o.z = f2bf((v1.z - mu) * rstd * gg.z + bb.z);
    o.w = f2bf((v1.w - mu) * rstd * gg.w + bb.w);
    *(ushort4*)(orow + 256 + lane * 4) = o;
}

// 4 square 512x512 weights in one launch (grid.z selects)
__global__ __launch_bounds__(256) void wconv4_kernel(const float* __restrict__ W0,
                                                     const float* __restrict__ W1,
                                                     const float* __restrict__ W2,
                                                     const float* __restrict__ W3,
                                                     ushort_t* __restrict__ Wt) {
    __shared__ float tile[32][33];
    const float* Ws[4] = {W0, W1, W2, W3};
    const float* W = Ws[blockIdx.z];
    ushort_t* Wd = Wt + (size_t)blockIdx.z * DIMX * DIMX;
    int bx = blockIdx.x * 32;
    int by = blockIdx.y * 32;
    int tx = threadIdx.x & 31, ty = threadIdx.x >> 5;
#pragma unroll
    for (int r = 0; r < 4; r++)
        tile[ty + r * 8][tx] = W[(size_t)(by + ty + r * 8) * DIMX + bx + tx];
    __syncthreads();
#pragma unroll
    for (int r = 0; r < 4; r++)
        Wd[(size_t)(bx + ty + r * 8) * DIMX + by + tx] = f2bf(tile[tx][ty + r * 8]);
}

// W1 [512,2048]->W1t and W2 [2048,512]->W2t in one launch (2048 blocks)
__global__ __launch_bounds__(256) void wconvFF_kernel(const float* __restrict__ W1,
                                                      const float* __restrict__ W2,
                                                      ushort_t* __restrict__ W1t,
                                                      ushort_t* __restrict__ W2t) {
    __shared__ float tile[32][33];
    int bid = blockIdx.x;
    const float* W;
    ushort_t* Wt;
    int K, N, bx, by;
    if (bid < 1024) {
        W = W1; Wt = W1t; K = 512; N = 2048;
        bx = (bid & 63) * 32; by = (bid >> 6) * 32;
    } else {
        bid -= 1024;
        W = W2; Wt = W2t; K = 2048; N = 512;
        bx = (bid & 15) * 32; by = (bid >> 4) * 32;
    }
    int tx = threadIdx.x & 31, ty = threadIdx.x >> 5;
#pragma unroll
    for (int r = 0; r < 4; r++)
        tile[ty + r * 8][tx] = W[(size_t)(by + ty + r * 8) * N + bx + tx];
    __syncthreads();
#pragma unroll
    for (int r = 0; r < 4; r++)
        Wt[(size_t)(bx + ty + r * 8) * K + by + tx] = f2bf(tile[tx][ty + r * 8]);
}

// ---------------- proj fp32 [266][64] -> bf16 [288][64] (pad rows zero); zero KMAX ----------
__global__ __launch_bounds__(256) void projconv_kernel(const float* __restrict__ proj,
                                                       ushort_t* __restrict__ Pbf,
                                                       unsigned int* __restrict__ KMAX) {
    int i = blockIdx.x * 256 + threadIdx.x;
    if (blockIdx.x == 0 && threadIdx.x < 4) KMAX[threadIdx.x] = 0u;
    if (i < MP * DHE) {
        int m = i >> 6;
        Pbf[i] = (m < NB) ? f2bf(proj[i]) : (ushort_t)0;
    }
}

// ---------------- fc weight split: fcw [512][32] fp32 -> Whi/Wlo [32 cols][512 k] bf16 ------
__global__ __launch_bounds__(256) void fcwconv_kernel(const float* __restrict__ W,
                                                      ushort_t* __restrict__ Whi,
                                                      ushort_t* __restrict__ Wlo) {
    int i = blockIdx.x * 256 + threadIdx.x;   // 16384
    if (i < 512 * 32) {
        int k = i >> 5, col = i & 31;
        float w = W[i];
        ushort_t h = f2bf(w);
        Whi[col * 512 + k] = h;
        Wlo[col * 512 + k] = f2bf(w - bf2f(h));
    }
}

// ---------------- bf16 MFMA GEMM: 128x128 tile, 16x16x32, 2-phase double-buffered ----------
// A[M,K] bf16 row-major; Bt[N,K] bf16 row-major. XCD-swizzled (nwg % 8 == 0).
// EPI 1: C = Cin + A@B + bias (fp32). EPI 2: Cb = bf16(gelu(A@B+bias)).
// EPI 4: transposed per-head bf16: Vt[(b*8+h)*64+d][8192].
// EPI 5: Cb = bf16(A@B) and SS[head][row] = sum over head cols of v^2.
template <int EPI>
__global__ __launch_bounds__(256) void gemm_mfma(const ushort_t* __restrict__ A,
                                                 const ushort_t* __restrict__ Bt,
                                                 const float* __restrict__ bias,
                                                 const float* Cin,
                                                 float* C,
                                                 ushort_t* __restrict__ Cb,
                                                 float* __restrict__ SS,
                                                 int M, int N, int K) {
    __shared__ ushort_t As[2][128 * 32];
    __shared__ ushort_t Bs[2][128 * 32];
    int t = threadIdx.x;
    int wave = t >> 6, lane = t & 63;
    int wm = wave >> 1, wn = wave & 1;
    // bijective XCD swizzle; decode n-fastest so each XCD owns a contiguous m-panel
    int gy = gridDim.y;
    int orig = blockIdx.x + blockIdx.y * gridDim.x;
    int cpx = (gridDim.x * gy) >> 3;
    int swz = (orig & 7) * cpx + (orig >> 3);
    int m0 = (swz / gy) * 128, n0 = (swz - (swz / gy) * gy) * 128;
    int q = lane >> 4, ml = lane & 15;

    floatx4 acc[4][4];
#pragma unroll
    for (int i = 0; i < 4; i++)
#pragma unroll
        for (int j = 0; j < 4; j++) acc[i][j] = (floatx4)(0.f);

    int srow = (lane >> 2);
    int scol = (lane & 3) * 8;
    const ushort_t* Ag = A + (size_t)(m0 + wave * 32 + srow) * K + scol;
    const ushort_t* Bg = Bt + (size_t)(n0 + wave * 32 + srow) * K + scol;
    ushort_t* AsW[2] = {&As[0][(wave * 32) * 32], &As[1][(wave * 32) * 32]};
    ushort_t* BsW[2] = {&Bs[0][(wave * 32) * 32], &Bs[1][(wave * 32) * 32]};

    gl_lds16(Ag, AsW[0]);
    gl_lds16(Ag + (size_t)16 * K, AsW[0] + 16 * 32);
    gl_lds16(Bg, BsW[0]);
    gl_lds16(Bg + (size_t)16 * K, BsW[0] + 16 * 32);
    __syncthreads();

    int cur = 0;
    for (int k0 = 32; k0 < K; k0 += 32) {
        int nxt = cur ^ 1;
        gl_lds16(Ag + k0, AsW[nxt]);
        gl_lds16(Ag + k0 + (size_t)16 * K, AsW[nxt] + 16 * 32);
        gl_lds16(Bg + k0, BsW[nxt]);
        gl_lds16(Bg + k0 + (size_t)16 * K, BsW[nxt] + 16 * 32);
        const ushort_t* Ac = &As[cur][0];
        const ushort_t* Bc = &Bs[cur][0];
        short8 a[4], b[4];
#pragma unroll
        for (int i = 0; i < 4; i++)
            a[i] = *(const short8*)&Ac[(wm * 64 + i * 16 + ml) * 32 + q * 8];
#pragma unroll
        for (int j = 0; j < 4; j++)
            b[j] = *(const short8*)&Bc[(wn * 64 + j * 16 + ml) * 32 + q * 8];
#pragma unroll
        for (int i = 0; i < 4; i++)
#pragma unroll
            for (int j = 0; j < 4; j++)
                acc[i][j] = __builtin_amdgcn_mfma_f32_16x16x32_bf16(a[i], b[j], acc[i][j], 0, 0, 0);
        __syncthreads();
        cur = nxt;
    }
    {
        const ushort_t* Ac = &As[cur][0];
        const ushort_t* Bc = &Bs[cur][0];
        short8 a[4], b[4];
#pragma unroll
        for (int i = 0; i < 4; i++)
            a[i] = *(const short8*)&Ac[(wm * 64 + i * 16 + ml) * 32 + q * 8];
#pragma unroll
        for (int j = 0; j < 4; j++)
            b[j] = *(const short8*)&Bc[(wn * 64 + j * 16 + ml) * 32 + q * 8];
#pragma unroll
        for (int i = 0; i < 4; i++)
#pragma unroll
            for (int j = 0; j < 4; j++)
                acc[i][j] = __builtin_amdgcn_mfma_f32_16x16x32_bf16(a[i], b[j], acc[i][j], 0, 0, 0);
    }

    if (EPI == 4) {
#pragma unroll
        for (int i = 0; i < 4; i++) {
            size_t r0 = (size_t)m0 + wm * 64 + i * 16 + q * 4;
            int bb = (int)(r0 >> 13);
            int nl = (int)(r0 & (SEQ - 1));
#pragma unroll
            for (int j = 0; j < 4; j++) {
                int col = n0 + wn * 64 + j * 16 + ml;
                int hh = col >> 6, dd = col & 63;
                ushort4 pk;
                pk.x = f2bf(acc[i][j][0]); pk.y = f2bf(acc[i][j][1]);
                pk.z = f2bf(acc[i][j][2]); pk.w = f2bf(acc[i][j][3]);
                *(ushort4*)&Cb[(((size_t)bb * 8 + hh) * DHE + dd) * SEQ + nl] = pk;
            }
        }
    } else if (EPI == 5) {
        int hh = (n0 >> 6) + wn;  // each wave's 64 cols = one head
#pragma unroll
        for (int i = 0; i < 4; i++) {
#pragma unroll
            for (int r = 0; r < 4; r++) {
                size_t row = (size_t)m0 + wm * 64 + i * 16 + q * 4 + r;
                float sq = 0.f;
#pragma unroll
                for (int j = 0; j < 4; j++) {
                    int col = n0 + wn * 64 + j * 16 + ml;
                    float v = acc[i][j][r];
                    sq += v * v;
                    Cb[row * N + col] = f2bf(v);
                }
                sq += __shfl_xor(sq, 1);
                sq += __shfl_xor(sq, 2);
                sq += __shfl_xor(sq, 4);
                sq += __shfl_xor(sq, 8);
                if (ml == 0) SS[(size_t)hh * PSEQ + row] = sq;
            }
        }
    } else {
#pragma unroll
        for (int i = 0; i < 4; i++) {
#pragma unroll
            for (int r = 0; r < 4; r++) {
                size_t row = (size_t)m0 + wm * 64 + i * 16 + q * 4 + r;
#pragma unroll
                for (int j = 0; j < 4; j++) {
                    int col = n0 + wn * 64 + j * 16 + ml;
                    float v = acc[i][j][r];
                    if (EPI == 1) {
                        C[row * N + col] = Cin[row * N + col] + v + bias[col];
                    } else if (EPI == 2) {
                        Cb[row * N + col] = f2bf(gelu_f(v + bias[col]));
                    }
                }
            }
        }
    }
}

// ---------------- fc via MFMA hi/lo split: out = X@W + b, fp32-equivalent accuracy ----------
// X split exactly: hi=bf16(x), lo=bf16(x-hi); out = hi@Whi + lo@Whi + hi@Wlo (err ~ 2^-18).
// grid 512 blocks x 256 thr; 64 rows/block; 12 KB LDS -> high occupancy; coalesced X reads.
__global__ __launch_bounds__(256) void fc_mfma_kernel(const float* __restrict__ A,
                                                      const ushort_t* __restrict__ Whi,
                                                      const ushort_t* __restrict__ Wlo,
                                                      const float* __restrict__ bias,
                                                      float* __restrict__ C) {
    __shared__ ushort_t As_hi[64 * 32], As_lo[64 * 32];
    __shared__ ushort_t Bs_hi[32 * 32], Bs_lo[32 * 32];
    int t = threadIdx.x;
    int w = t >> 6, lane = t & 63;
    int q = lane >> 4, ml = lane & 15;
    size_t m0 = (size_t)blockIdx.x * 64;
    floatx4 acc0 = (floatx4)(0.f), acc1 = (floatx4)(0.f);
    int srow = t >> 2, skq = (t & 3) * 8;   // X staging: 64 rows x 32 k / 256 thr = 8 floats
    int bcol = t >> 3, bkq = (t & 7) * 4;   // W staging: 32x32 / 256 thr = 4 shorts
    for (int k0 = 0; k0 < DIMX; k0 += 32) {
        const float* xp = A + (m0 + srow) * DIMX + k0 + skq;
        float4 v0 = *(const float4*)xp;
        float4 v1 = *(const float4*)(xp + 4);
        float vv[8] = {v0.x, v0.y, v0.z, v0.w, v1.x, v1.y, v1.z, v1.w};
        ushort_t hh[8], ll[8];
#pragma unroll
        for (int e = 0; e < 8; e++) {
            hh[e] = f2bf(vv[e]);
            ll[e] = f2bf(vv[e] - bf2f(hh[e]));
        }
        ushort4 u;
        u.x = hh[0]; u.y = hh[1]; u.z = hh[2]; u.w = hh[3];
        *(ushort4*)&As_hi[srow * 32 + skq] = u;
        u.x = hh[4]; u.y = hh[5]; u.z = hh[6]; u.w = hh[7];
        *(ushort4*)&As_hi[srow * 32 + skq + 4] = u;
        u.x = ll[0]; u.y = ll[1]; u.z = ll[2]; u.w = ll[3];
        *(ushort4*)&As_lo[srow * 32 + skq] = u;
        u.x = ll[4]; u.y = ll[5]; u.z = ll[6]; u.w = ll[7];
        *(ushort4*)&As_lo[srow * 32 + skq + 4] = u;
        *(ushort4*)&Bs_hi[bcol * 32 + bkq] = *(const ushort4*)&Whi[bcol * 512 + k0 + bkq];
        *(ushort4*)&Bs_lo[bcol * 32 + bkq] = *(const ushort4*)&Wlo[bcol * 512 + k0 + bkq];
        __syncthreads();
        short8 ah = *(const short8*)&As_hi[(w * 16 + ml) * 32 + q * 8];
        short8 al = *(const short8*)&As_lo[(w * 16 + ml) * 32 + q * 8];
        short8 bh0 = *(const short8*)&Bs_hi[ml * 32 + q * 8];
        short8 bh1 = *(const short8*)&Bs_hi[(16 + ml) * 32 + q * 8];
        short8 bl0 = *(const short8*)&Bs_lo[ml * 32 + q * 8];
        short8 bl1 = *(const short8*)&Bs_lo[(16 + ml) * 32 + q * 8];
        acc0 = __builtin_amdgcn_mfma_f32_16x16x32_bf16(ah, bh0, acc0, 0, 0, 0);
        acc0 = __builtin_amdgcn_mfma_f32_16x16x32_bf16(al, bh0, acc0, 0, 0, 0);
        acc0 = __builtin_amdgcn_mfma_f32_16x16x32_bf16(ah, bl0, acc0, 0, 0, 0);
        acc1 = __builtin_amdgcn_mfma_f32_16x16x32_bf16(ah, bh1, acc1, 0, 0, 0);
        acc1 = __builtin_amdgcn_mfma_f32_16x16x32_bf16(al, bh1, acc1, 0, 0, 0);
        acc1 = __builtin_amdgcn_mfma_f32_16x16x32_bf16(ah, bl1, acc1, 0, 0, 0);
        __syncthreads();
    }
    float bb0 = bias[ml], bb1 = bias[16 + ml];
#pragma unroll
    for (int r = 0; r < 4; r++) {
        size_t row = m0 + w * 16 + q * 4 + r;
        C[row * OUTD + ml] = acc0[r] + bb0;
        C[row * OUTD + 16 + ml] = acc1[r] + bb1;
    }
}

// ---------------- global key-feature max via MFMA: grid 512 = 8 heads x 64 tiles ------------
__global__ __launch_bounds__(512) void kmax_kernel(const ushort_t* __restrict__ Kbf,
                                                   const ushort_t* __restrict__ Pbf,
                                                   unsigned int* __restrict__ kmaxkey) {
    __shared__ float wred[8];
    int tid = threadIdx.x;
    int w = tid >> 6, lane = tid & 63;
    int q = lane >> 4, ml = lane & 15;
    int h = blockIdx.x >> 6, tile = blockIdx.x & 63;
    float lm = -3.0e38f;
#pragma unroll
    for (int sub = 0; sub < 2; sub++) {
        int arow = tile * 256 + sub * 128 + w * 16 + ml;
        short8 af0 = *(const short8*)&Kbf[(size_t)arow * DIMX + h * DHE + q * 8];
        short8 af1 = *(const short8*)&Kbf[(size_t)arow * DIMX + h * DHE + 32 + q * 8];
#pragma unroll
        for (int c = 0; c < 17; c++) {
            floatx4 xp = (floatx4)(0.f);
            short8 b0 = *(const short8*)&Pbf[(c * 16 + ml) * DHE + q * 8];
            short8 b1 = *(const short8*)&Pbf[(c * 16 + ml) * DHE + 32 + q * 8];
            xp = __builtin_amdgcn_mfma_f32_16x16x32_bf16(af0, b0, xp, 0, 0, 0);
            xp = __builtin_amdgcn_mfma_f32_16x16x32_bf16(af1, b1, xp, 0, 0, 0);
            if (c * 16 + ml < NB)
                lm = fmaxf(lm, fmaxf(fmaxf(xp[0], xp[1]), fmaxf(xp[2], xp[3])));
        }
    }
    lm *= DN_F;
#pragma unroll
    for (int off = 32; off; off >>= 1) lm = fmaxf(lm, __shfl_xor(lm, off));
    if (lane == 0) wred[w] = lm;
    __syncthreads();
    if (tid == 0) {
        float bm = wred[0];
#pragma unroll
        for (int ww = 1; ww < 8; ww++) bm = fmaxf(bm, wred[ww]);
        atomicMax(kmaxkey, fkey(bm));
    }
}

// ---------------- fused kp + CTX partial via MFMA (half-split kpT, 2 blocks/CU) ------------
__global__ __launch_bounds__(512, 4) void kctx_kernel(const ushort_t* __restrict__ Kbf,
                                                      const ushort_t* __restrict__ Pbf,
                                                      const float* __restrict__ SS,
                                                      const unsigned int* __restrict__ kmaxkey,
                                                      const ushort_t* __restrict__ Vt,
                                                      float* __restrict__ CTXP,
                                                      float* __restrict__ KSUM) {
    __shared__ ushort_t kpT[144 * KPT_LD];   // 39168 B; reused as float[144][68] for output
    __shared__ float ksum_l[MP];
    int tid = threadIdx.x;
    int w = tid >> 6, lane = tid & 63;
    int q = lane >> 4, ml = lane & 15;
    int bh = blockIdx.x >> 5, s = blockIdx.x & 31;
    int b = bh >> 3, h = bh & 7;
    float mx = funkey(*kmaxkey);
    if (tid < MP) ksum_l[tid] = 0.f;
    __syncthreads();
    floatx4 ctxa[2][5];
#pragma unroll
    for (int hf = 0; hf < 2; hf++)
#pragma unroll
        for (int i = 0; i < 5; i++) ctxa[hf][i] = (floatx4)(0.f);

#pragma unroll
    for (int sub = 0; sub < 2; sub++) {
        int tb = b * SEQ + s * 256 + sub * 128;
        int arow = tb + w * 16 + ml;
        short8 af0 = *(const short8*)&Kbf[(size_t)arow * DIMX + h * DHE + q * 8];
        short8 af1 = *(const short8*)&Kbf[(size_t)arow * DIMX + h * DHE + 32 + q * 8];
        float ssr[4];
#pragma unroll
        for (int r = 0; r < 4; r++) ssr[r] = SS[h * PSEQ + tb + w * 16 + q * 4 + r];
#pragma unroll
        for (int hf = 0; hf < 2; hf++) {
#pragma unroll
            for (int cl = 0; cl < 9; cl++) {
                int c = hf * 9 + cl;
                floatx4 xp = (floatx4)(0.f);
                short8 b0 = *(const short8*)&Pbf[(c * 16 + ml) * DHE + q * 8];
                short8 b1 = *(const short8*)&Pbf[(c * 16 + ml) * DHE + 32 + q * 8];
                xp = __builtin_amdgcn_mfma_f32_16x16x32_bf16(af0, b0, xp, 0, 0, 0);
                xp = __builtin_amdgcn_mfma_f32_16x16x32_bf16(af1, b1, xp, 0, 0, 0);
                int m = c * 16 + ml;
                bool val = m < NB;
                float kpv[4];
#pragma unroll
                for (int r = 0; r < 4; r++)
                    kpv[r] = val ? RATIO_F * (__expf(xp[r] * DN_F - ssr[r] * 0.0625f - mx) + EPS_F)
                                 : 0.f;
                ushort4 pk;
                pk.x = f2bf(kpv[0]); pk.y = f2bf(kpv[1]);
                pk.z = f2bf(kpv[2]); pk.w = f2bf(kpv[3]);
                *(ushort4*)&kpT[(cl * 16 + ml) * KPT_LD + w * 16 + q * 4] = pk;
                float s4 = kpv[0] + kpv[1] + kpv[2] + kpv[3];
                s4 += __shfl_xor(s4, 16);
                s4 += __shfl_xor(s4, 32);
                if (q == 0) atomicAdd(&ksum_l[m], s4);
            }
            __syncthreads();
#pragma unroll
            for (int sk = 0; sk < 4; sk++) {
#pragma unroll
                for (int i = 0; i < 5; i++) {
                    if (i < 4 || w < 4) {
                        int tt = w + i * 8;
                        int mtl = tt >> 2, dt = tt & 3;
                        short8 a = *(const short8*)&kpT[(mtl * 16 + ml) * KPT_LD + sk * 32 + q * 8];
                        short8 bv = *(const short8*)&Vt[((size_t)bh * DHE + dt * 16 + ml) * SEQ +
                                                        s * 256 + sub * 128 + sk * 32 + q * 8];
                        ctxa[hf][i] = __builtin_amdgcn_mfma_f32_16x16x32_bf16(a, bv, ctxa[hf][i], 0, 0, 0);
                    }
                }
            }
            __syncthreads();
        }
    }
    // --- coalesced output: stage each half through LDS, stream float4 ---
    float* stg = (float*)kpT;   // [144][68] floats
    float* cp = CTXP + ((size_t)bh * NSTRIP + s) * (MP * DHE);
#pragma unroll
    for (int hf = 0; hf < 2; hf++) {
        __syncthreads();
#pragma unroll
        for (int i = 0; i < 5; i++) {
            if (i < 4 || w < 4) {
                int tt = w + i * 8;
                int mtl = tt >> 2, dt = tt & 3;
#pragma unroll
                for (int r = 0; r < 4; r++)
                    stg[(mtl * 16 + q * 4 + r) * 68 + dt * 16 + ml] = ctxa[hf][i][r];
            }
        }
        __syncthreads();
        float4* cp4 = (float4*)(cp + (size_t)hf * 144 * DHE);
        for (int e4 = tid; e4 < 2304; e4 += 512) {
            int row = e4 >> 4, col4 = e4 & 15;
            cp4[e4] = ((const float4*)stg)[row * 17 + col4];
        }
    }
    if (tid < MP) atomicAdd(&KSUM[bh * MP + tid], ksum_l[tid]);
}

// -------- reduce CTX partials over 32 strips; emit bf16 CTX^T [bh][64][296] --------
__global__ __launch_bounds__(256) void ctx_reduce_kernel(const float* __restrict__ CTXP,
                                                         ushort_t* __restrict__ CTXbf) {
    int i = blockIdx.x * 256 + threadIdx.x;  // 16*288*64
    if (i < 16 * MP * DHE) {
        int bh = i / (MP * DHE);
        int e = i - bh * (MP * DHE);
        float s = 0.f;
#pragma unroll
        for (int st = 0; st < NSTRIP; st++)
            s += CTXP[((size_t)bh * NSTRIP + st) * (MP * DHE) + e];
        int m = e >> 6, d = e & 63;
        CTXbf[((size_t)bh * DHE + d) * CTXT_LD + m] = f2bf(s);
    }
}

// ---------------- fused qp + rowmax + denom + O = dinv*(qp@CTX) via MFMA ----------------
__global__ __launch_bounds__(256, 3) void qo_kernel(const ushort_t* __restrict__ Qbf,
                                                    const ushort_t* __restrict__ Pbf,
                                                    const float* __restrict__ SS,
                                                    const ushort_t* __restrict__ CTXbf,
                                                    const float* __restrict__ KSUM,
                                                    ushort_t* __restrict__ Ob) {
    __shared__ ushort_t ctxt[DHE * CTXT_LD];
    __shared__ ushort_t qpA[4][16][40];
    __shared__ float ksl[MP];
    int tid = threadIdx.x;
    int w = tid >> 6, lane = tid & 63;
    int q = lane >> 4, ml = lane & 15;
    int bh = blockIdx.x >> 7, tile = blockIdx.x & 127;
    int b = bh >> 3, h = bh & 7;
    const short8* Cg8 = (const short8*)(CTXbf + (size_t)bh * (DHE * CTXT_LD));
    short8* ct8 = (short8*)ctxt;
    for (int e = tid; e < (DHE * CTXT_LD) / 8; e += 256)
        ct8[e] = Cg8[e];
    ksl[tid] = KSUM[bh * MP + tid];
    if (tid < MP - 256) ksl[256 + tid] = KSUM[bh * MP + 256 + tid];
    __syncthreads();
    int nl = tile * 64 + w * 16;
    int arow = b * SEQ + nl + ml;
    short8 af0 = *(const short8*)&Qbf[(size_t)arow * DIMX + h * DHE + q * 8];
    short8 af1 = *(const short8*)&Qbf[(size_t)arow * DIMX + h * DHE + 32 + q * 8];
    floatx4 xp[MT];
#pragma unroll
    for (int c = 0; c < MT; c++) {
        xp[c] = (floatx4)(0.f);
        short8 b0 = *(const short8*)&Pbf[(c * 16 + ml) * DHE + q * 8];
        short8 b1 = *(const short8*)&Pbf[(c * 16 + ml) * DHE + 32 + q * 8];
        xp[c] = __builtin_amdgcn_mfma_f32_16x16x32_bf16(af0, b0, xp[c], 0, 0, 0);
        xp[c] = __builtin_amdgcn_mfma_f32_16x16x32_bf16(af1, b1, xp[c], 0, 0, 0);
    }
    float ssr[4], rm[4], dp[4], dinv[4];
#pragma unroll
    for (int r = 0; r < 4; r++) {
        ssr[r] = SS[h * PSEQ + b * SEQ + nl + q * 4 + r];
        rm[r] = -3.0e38f;
        dp[r] = 0.f;
    }
#pragma unroll
    for (int c = 0; c < MT; c++) {
        int m = c * 16 + ml;
        bool val = m < NB;
#pragma unroll
        for (int r = 0; r < 4; r++) {
            float tv = xp[c][r] * DN_F;
            xp[c][r] = tv;
            if (val) rm[r] = fmaxf(rm[r], tv);
        }
    }
#pragma unroll
    for (int r = 0; r < 4; r++) {
        rm[r] = fmaxf(rm[r], __shfl_xor(rm[r], 1));
        rm[r] = fmaxf(rm[r], __shfl_xor(rm[r], 2));
        rm[r] = fmaxf(rm[r], __shfl_xor(rm[r], 4));
        rm[r] = fmaxf(rm[r], __shfl_xor(rm[r], 8));
    }
#pragma unroll
    for (int c = 0; c < MT; c++) {
        int m = c * 16 + ml;
        bool val = m < NB;
        float km = ksl[m];
#pragma unroll
        for (int r = 0; r < 4; r++) {
            float v = val ? RATIO_F * (__expf(xp[c][r] - ssr[r] * 0.0625f - rm[r]) + EPS_F) : 0.f;
            xp[c][r] = v;
            dp[r] += v * km;
        }
    }
#pragma unroll
    for (int r = 0; r < 4; r++) {
        dp[r] += __shfl_xor(dp[r], 1);
        dp[r] += __shfl_xor(dp[r], 2);
        dp[r] += __shfl_xor(dp[r], 4);
        dp[r] += __shfl_xor(dp[r], 8);
        dinv[r] = 1.0f / dp[r];
    }
    floatx4 oacc[4];
#pragma unroll
    for (int dt = 0; dt < 4; dt++) oacc[dt] = (floatx4)(0.f);
#pragma unroll
    for (int ks = 0; ks < 9; ks++) {
#pragma unroll
        for (int cc = 0; cc < 2; cc++) {
            int c = 2 * ks + cc;
#pragma unroll
            for (int r = 0; r < 4; r++)
                qpA[w][q * 4 + r][cc * 16 + ml] = f2bf(xp[c][r]);
        }
        short8 a = *(const short8*)&qpA[w][ml][q * 8];
#pragma unroll
        for (int dt = 0; dt < 4; dt++) {
            short8 bv = *(const short8*)&ctxt[(dt * 16 + ml) * CTXT_LD + ks * 32 + q * 8];
            oacc[dt] = __builtin_amdgcn_mfma_f32_16x16x32_bf16(a, bv, oacc[dt], 0, 0, 0);
        }
    }
#pragma unroll
    for (int dt = 0; dt < 4; dt++)
#pragma unroll
        for (int r = 0; r < 4; r++)
            Ob[(size_t)(b * SEQ + nl + q * 4 + r) * DIMX + h * DHE + dt * 16 + ml] =
                f2bf(oacc[dt][r] * dinv[r]);
}

extern "C" void kernel_launch(void* const* d_in, const int* in_sizes, int n_in,
                              void* d_out, int out_size, void* d_ws, size_t ws_size,
                              hipStream_t stream) {
    (void)in_sizes; (void)n_in; (void)out_size; (void)ws_size;
    const float* src  = (const float*)d_in[0];
    const float* proj = (const float*)d_in[1];
    const float* ln1g = (const float*)d_in[2];
    const float* ln1b = (const float*)d_in[3];
    const float* Wq   = (const float*)d_in[4];
    const float* Wk   = (const float*)d_in[5];
    const float* Wv   = (const float*)d_in[6];
    const float* Wo   = (const float*)d_in[7];
    const float* bo   = (const float*)d_in[8];
    const float* ln2g = (const float*)d_in[9];
    const float* ln2b = (const float*)d_in[10];
    const float* W1   = (const float*)d_in[11];
    const float* b1   = (const float*)d_in[12];
    const float* W2   = (const float*)d_in[13];
    const float* b2   = (const float*)d_in[14];
    const float* fcw  = (const float*)d_in[15];
    const float* fcb  = (const float*)d_in[16];
    float* out = (float*)d_out;

    // ---- workspace layout (~155 MiB of 162 safe) ----
    const size_t TD   = (size_t)NTOK * DIMX;
    const size_t PD   = (size_t)PSEQ * DIMX;
    float*    X    = (float*)d_ws;                      // 64 MiB residual fp32
    ushort_t* Hs   = (ushort_t*)(X + TD);               // 16 MiB LN out bf16 (pair)
    ushort_t* KQbf = Hs + PD;                           // 16 MiB K bf16, then Q bf16
    ushort_t* Vt   = KQbf + PD;                         // 16 MiB V^T per-head bf16
    float*    CTXP = (float*)(Vt + PD);                 // 36 MiB ctx partials (32 strips)
    ushort_t* Obuf = (ushort_t*)CTXP;                   // 16 MiB attn-out bf16, aliases CTXP
    ushort_t* CTXbf = (ushort_t*)(CTXP + (size_t)16 * NSTRIP * MP * DHE);  // bf16 CTX^T
    float*    KSUM = (float*)(CTXbf + (size_t)16 * DHE * CTXT_LD);  // 16x288
    unsigned int* KMAX = (unsigned int*)(KSUM + 16 * MP);
    float*    SS   = (float*)(KMAX + 4);                // [8][PSEQ]
    ushort_t* Pbf  = (ushort_t*)(SS + (size_t)NHEADS * PSEQ);  // [288][64] bf16
    ushort_t* Wtb  = Pbf + MP * DHE;                    // 6 MiB weights bf16
    ushort_t* Wqt = Wtb;
    ushort_t* Wkt = Wqt + DIMX * DIMX;
    ushort_t* Wvt = Wkt + DIMX * DIMX;
    ushort_t* Wot = Wvt + DIMX * DIMX;
    ushort_t* W1t = Wot + DIMX * DIMX;         // [FFD, DIMX]
    ushort_t* W2t = W1t + (size_t)DIMX * FFD;  // [DIMX, FFD]
    ushort_t* Wfhi = W2t + (size_t)FFD * DIMX; // [32][512] bf16 fc hi
    ushort_t* Wflo = Wfhi + 32 * 512;          // [32][512] bf16 fc lo
    ushort_t* Hid = KQbf;  // FF hidden 64 MiB alias (all dead in FF)

    dim3 gP(PSEQ / 128, DIMX / 128);   // (128,4)  nwg=512
    dim3 gF1(PSEQ / 128, FFD / 128);   // (128,16) nwg=2048
    const int lnGrid = PSEQ / 4;
    fcwconv_kernel<<<64, 256, 0, stream>>>(fcw, Wfhi, Wflo);
    for (int L = 0; L < NLAYER; L++) {
        const float* pj = proj + (size_t)L * NB * DHE;
        wconv4_kernel<<<dim3(16, 16, 4), 256, 0, stream>>>(
            Wq + (size_t)L * DIMX * DIMX, Wk + (size_t)L * DIMX * DIMX,
            Wv + (size_t)L * DIMX * DIMX, Wo + (size_t)L * DIMX * DIMX, Wqt);
        wconvFF_kernel<<<2048, 256, 0, stream>>>(W1 + (size_t)L * DIMX * FFD,
                                                 W2 + (size_t)L * FFD * DIMX, W1t, W2t);
        projconv_kernel<<<(MP * DHE + 255) / 256, 256, 0, stream>>>(pj, Pbf, KMAX);
        // --- phase A: global key-feature max over both pairs ---
        for (int p = 0; p < 2; p++) {
            const float* XpIn = (L == 0) ? (src + (size_t)p * PD) : (X + (size_t)p * PD);
            ln_bf16_kernel<<<lnGrid, 256, 0, stream>>>(XpIn, ln1g + L * DIMX, ln1b + L * DIMX, Hs);
            gemm_mfma<5><<<gP, 256, 0, stream>>>(Hs, Wkt, nullptr, nullptr, nullptr, KQbf, SS, PSEQ, DIMX, DIMX);
            kmax_kernel<<<512, 512, 0, stream>>>(KQbf, Pbf, KMAX);
        }
        // --- phase B: attention + FF per pair (p=1 first: Hs/KQbf/SS still hold pair-1) ---
        for (int pp = 0; pp < 2; pp++) {
            int p = 1 - pp;
            float* Xp = X + (size_t)p * PD;
            const float* XpIn = (L == 0) ? (src + (size_t)p * PD) : Xp;
            if (p == 0) {
                ln_bf16_kernel<<<lnGrid, 256, 0, stream>>>(XpIn, ln1g + L * DIMX, ln1b + L * DIMX, Hs);
                gemm_mfma<5><<<gP, 256, 0, stream>>>(Hs, Wkt, nullptr, nullptr, nullptr, KQbf, SS, PSEQ, DIMX, DIMX);
            }
            gemm_mfma<4><<<gP, 256, 0, stream>>>(Hs, Wvt, nullptr, nullptr, nullptr, Vt, nullptr, PSEQ, DIMX, DIMX);
            zero_kernel<<<(16 * MP + 255) / 256, 256, 0, stream>>>(KSUM, 16 * MP);
            kctx_kernel<<<16 * NSTRIP, 512, 0, stream>>>(KQbf, Pbf, SS, KMAX, Vt, CTXP, KSUM);
            ctx_reduce_kernel<<<(16 * MP * DHE + 255) / 256, 256, 0, stream>>>(CTXP, CTXbf);
            gemm_mfma<5><<<gP, 256, 0, stream>>>(Hs, Wqt, nullptr, nullptr, nullptr, KQbf, SS, PSEQ, DIMX, DIMX);
            qo_kernel<<<2048, 256, 0, stream>>>(KQbf, Pbf, SS, CTXbf, KSUM, Obuf);
            // Wo: X = XpIn + Obuf@Wo + bo (layer 0 reads src, writes X)
            gemm_mfma<1><<<gP, 256, 0, stream>>>(Obuf, Wot, bo + L * DIMX, XpIn, Xp, nullptr, nullptr, PSEQ, DIMX, DIMX);
            // --- FF ---
            ln_bf16_kernel<<<lnGrid, 256, 0, stream>>>(Xp, ln2g + L * DIMX, ln2b + L * DIMX, Hs);
            gemm_mfma<2><<<gF1, 256, 0, stream>>>(Hs, W1t, b1 + L * FFD, nullptr, nullptr, Hid, nullptr, PSEQ, FFD, DIMX);
            gemm_mfma<1><<<gP, 256, 0, stream>>>(Hid, W2t, b2 + L * DIMX, Xp, Xp, nullptr, nullptr, PSEQ, DIMX, FFD);
        }
    }
    fc_mfma_kernel<<<NTOK / 64, 256, 0, stream>>>(X, Wfhi, Wflo, fcb, out);
}